// Round 5
// baseline (533.509 us; speedup 1.0000x reference)
//
#include <hip/hip_runtime.h>

// BiGRU, B=512, T=512, D=16, H=64.
// Backward direction needs only ONE cell step (ys_b[0] = GRUCell(x[:,T-1,:], 0)).
//
// Round-4 lesson: the 4-wave K-split pays a per-step __syncthreads (full
// vmcnt/lgkm drain x512 steps) + two serialized LDS round-trips; measured
// ~1780 cyc/step vs ~500 modeled. Rounds 1-3 lesson: arch VGPRs cap at 256;
// 192 weight floats + temps => AGPR copy traffic.
//
// This version: ONE wave per batch, ZERO barriers:
//  - w_r, w_z rows in 128 VGPRs; n-gate weights STREAMED from LDS
//    (loaded once, row-padded +4 -> uniform 8/bank = pure-BW floor,
//    address-static reads prefetch under the FMA stream).
//  - h broadcast hybrid: h[0:16) via v_readlane (immediate), h[16:64) via
//    broadcast ds_read_b128 from a double-buffered hbuf (same-wave LDS is
//    in-order: write h -> read back needs NO barrier). The readlane-fed
//    FMAs cover the LDS broadcast latency.
//  - input projection computed inline per step (no xg round-trip).
//  - 512 blocks x 64 thr; ~230 arch VGPRs -> no AGPR spill by construction.

#define Hh 64
#define Dd 16
#define Tt 512
#define Bb 512
#define CH 64    // timesteps per x chunk
#define WNP 68   // padded LDS row stride for wn (68*4B=272B: 16B-aligned, banks spread)

__device__ __forceinline__ float sigmoid_fast(float v) {
    return 1.0f / (1.0f + __expf(-v));
}
__device__ __forceinline__ float tanh_fast(float v) {
    float e = __expf(2.0f * v);
    return 1.0f - 2.0f / (e + 1.0f);
}
__device__ __forceinline__ float lane_bcast(float v, int k) {
    return __int_as_float(__builtin_amdgcn_readlane(__float_as_int(v), k));
}
__device__ __forceinline__ float dot4(float4 a, float4 b) {
    return a.x * b.x + a.y * b.y + a.z * b.z + a.w * b.w;
}

__global__ __launch_bounds__(64, 1)
void bigru_fused_kernel(const float* __restrict__ x,
                        const float* __restrict__ w_ih_f, const float* __restrict__ w_hh_f,
                        const float* __restrict__ b_ih_f, const float* __restrict__ b_hh_f,
                        const float* __restrict__ w_ih_b, const float* __restrict__ w_hh_b,
                        const float* __restrict__ b_ih_b, const float* __restrict__ b_hh_b,
                        const float* __restrict__ fc_w,  const float* __restrict__ fc_b,
                        float* __restrict__ out)
{
    const int j = threadIdx.x;   // hidden unit 0..63 (single wave)
    const int b = blockIdx.x;    // batch element

    __shared__ float wn_lds[Hh * WNP];             // 17408 B: n-gate weights, padded
    __shared__ __align__(16) float xbuf[CH * Dd];  // 4096 B: raw x chunk
    __shared__ __align__(16) float hbuf[2][Hh];    // 512 B: h broadcast, double-buffered

    // ---- one-time: stage n-gate weight rows [128..192) of w_hh_f into LDS ----
    {
        const float4* src = (const float4*)(w_hh_f + 2 * Hh * Hh);
#pragma unroll
        for (int q = 0; q < 16; ++q) {
            float4 v = src[q * 64 + j];
            int flat = (q * 64 + j) * 4;          // 0..4095, multiple of 4
            int row = flat >> 6, col = flat & 63; // col % 4 == 0 -> 16B aligned
            *(float4*)(wn_lds + row * WNP + col) = v;
        }
    }

    // ---- r,z recurrent weight rows {j, 64+j} in 128 VGPRs ----
    float wr[Hh], wz[Hh];
    {
        const float4* r0 = (const float4*)(w_hh_f + (size_t)j * Hh);
        const float4* r1 = (const float4*)(w_hh_f + (size_t)(Hh + j) * Hh);
#pragma unroll
        for (int q = 0; q < Hh / 4; ++q) {
            float4 a = r0[q]; wr[4*q] = a.x; wr[4*q+1] = a.y; wr[4*q+2] = a.z; wr[4*q+3] = a.w;
            float4 c = r1[q]; wz[4*q] = c.x; wz[4*q+1] = c.y; wz[4*q+2] = c.z; wz[4*q+3] = c.w;
        }
    }
    // ---- input-projection weights (48 regs) + biases ----
    float4 wir[4], wiz[4], win[4];
    {
        const float4* p0 = (const float4*)(w_ih_f + (size_t)j            * Dd);
        const float4* p1 = (const float4*)(w_ih_f + (size_t)(Hh + j)     * Dd);
        const float4* p2 = (const float4*)(w_ih_f + (size_t)(2 * Hh + j) * Dd);
#pragma unroll
        for (int q = 0; q < 4; ++q) { wir[q] = p0[q]; wiz[q] = p1[q]; win[q] = p2[q]; }
    }
    const float bxr = b_ih_f[j]          + b_hh_f[j];
    const float bxz = b_ih_f[Hh + j]     + b_hh_f[Hh + j];
    const float bxn = b_ih_f[2 * Hh + j];
    const float bhn = b_hh_f[2 * Hh + j];

    float h = 0.0f;
    hbuf[0][j] = 0.0f;   // single wave: in-order LDS, no barrier needed anywhere

    const float* xrow = x + (size_t)b * Tt * Dd;
    const float4* wn4 = (const float4*)(wn_lds + j * WNP);  // lane j's n-row

    for (int tc = 0; tc < Tt / CH; ++tc) {
        // stage 64 timesteps (1024 floats = 256 float4): 4 per lane, coalesced
        {
            const float4* src = (const float4*)(xrow + (size_t)tc * CH * Dd);
            float4* dst = (float4*)xbuf;
#pragma unroll
            for (int q = 0; q < 4; ++q) dst[q * 64 + j] = src[q * 64 + j];
        }

        for (int tt = 0; tt < CH; ++tt) {
            const int t   = tc * CH + tt;
            const int cur = t & 1;

            // ---- input projection inline (x_t broadcast from LDS) ----
            const float4* x4 = (const float4*)(xbuf + tt * Dd);
            float4 xv0 = x4[0], xv1 = x4[1], xv2 = x4[2], xv3 = x4[3];
            float ar = bxr + dot4(wir[0], xv0) + dot4(wir[1], xv1)
                           + dot4(wir[2], xv2) + dot4(wir[3], xv3);
            float az = bxz + dot4(wiz[0], xv0) + dot4(wiz[1], xv1)
                           + dot4(wiz[2], xv2) + dot4(wiz[3], xv3);
            float xn = bxn + dot4(win[0], xv0) + dot4(win[1], xv1)
                           + dot4(win[2], xv2) + dot4(win[3], xv3);
            float an = bhn;
            // second accumulator set to shorten dependent chains
            float ar1 = 0.0f, az1 = 0.0f, an1 = 0.0f;

            const float4* hb4 = (const float4*)(hbuf[cur]);

            // ---- recurrent matvec: q<4 h via readlane, q>=4 via LDS broadcast;
            //      n-gate weights streamed from LDS (address-static) ----
#pragma unroll
            for (int q = 0; q < 16; ++q) {
                float4 wnv = wn4[q];
                float4 hv;
                if (q < 4) {
                    hv.x = lane_bcast(h, 4*q+0); hv.y = lane_bcast(h, 4*q+1);
                    hv.z = lane_bcast(h, 4*q+2); hv.w = lane_bcast(h, 4*q+3);
                } else {
                    hv = hb4[q];
                }
                ar  = fmaf(wr[4*q+0], hv.x, ar);  ar1 = fmaf(wr[4*q+1], hv.y, ar1);
                ar  = fmaf(wr[4*q+2], hv.z, ar);  ar1 = fmaf(wr[4*q+3], hv.w, ar1);
                az  = fmaf(wz[4*q+0], hv.x, az);  az1 = fmaf(wz[4*q+1], hv.y, az1);
                az  = fmaf(wz[4*q+2], hv.z, az);  az1 = fmaf(wz[4*q+3], hv.w, az1);
                an  = fmaf(wnv.x,     hv.x, an);  an1 = fmaf(wnv.y,     hv.y, an1);
                an  = fmaf(wnv.z,     hv.z, an);  an1 = fmaf(wnv.w,     hv.w, an1);
            }
            ar += ar1; az += az1; an += an1;

            // ---- gates + state update ----
            float r = sigmoid_fast(ar);
            float z = sigmoid_fast(az);
            float n = tanh_fast(xn + r * an);
            h = n + z * (h - n);   // (1-z)*n + z*h

            hbuf[cur ^ 1][j] = h;  // next step reads hbuf[(t+1)&1] -- in-order, no barrier
        }
    }

    // ---- backward direction: single cell step from h=0 on x[:,T-1,:] ----
    // xbuf still holds last chunk; t=511 is slot CH-1=63.
    float ar   = b_ih_b[j]          + b_hh_b[j];
    float az   = b_ih_b[Hh + j]     + b_hh_b[Hh + j];
    float axn  = b_ih_b[2 * Hh + j];
    float bhnb = b_hh_b[2 * Hh + j];
    {
        const float4* xl = (const float4*)(xbuf + (CH - 1) * Dd);
        const float4* q0 = (const float4*)(w_ih_b + (size_t)j            * Dd);
        const float4* q1 = (const float4*)(w_ih_b + (size_t)(Hh + j)     * Dd);
        const float4* q2 = (const float4*)(w_ih_b + (size_t)(2 * Hh + j) * Dd);
#pragma unroll
        for (int q = 0; q < 4; ++q) {
            float4 xv = xl[q];
            float4 a = q0[q], c = q1[q], e = q2[q];
            ar  += a.x * xv.x + a.y * xv.y + a.z * xv.z + a.w * xv.w;
            az  += c.x * xv.x + c.y * xv.y + c.z * xv.z + c.w * xv.w;
            axn += e.x * xv.x + e.y * xv.y + e.z * xv.z + e.w * xv.w;
        }
    }
    float rb = sigmoid_fast(ar);
    float zb = sigmoid_fast(az);
    float nb = tanh_fast(axn + rb * bhnb);
    float hb = (1.0f - zb) * nb;   // h0 = 0

    // ---- fused FC: y[b] = fc_w[0:64].h_fwd + fc_w[64:128].h_bwd + fc_b ----
    float v = fc_w[j] * h + fc_w[Hh + j] * hb;
#pragma unroll
    for (int off = 32; off > 0; off >>= 1)
        v += __shfl_xor(v, off, 64);
    if (j == 0) out[b] = v + fc_b[0];
}

extern "C" void kernel_launch(void* const* d_in, const int* in_sizes, int n_in,
                              void* d_out, int out_size, void* d_ws, size_t ws_size,
                              hipStream_t stream) {
    const float* x      = (const float*)d_in[0];
    const float* w_ih_f = (const float*)d_in[1];
    const float* w_hh_f = (const float*)d_in[2];
    const float* b_ih_f = (const float*)d_in[3];
    const float* b_hh_f = (const float*)d_in[4];
    const float* w_ih_b = (const float*)d_in[5];
    const float* w_hh_b = (const float*)d_in[6];
    const float* b_ih_b = (const float*)d_in[7];
    const float* b_hh_b = (const float*)d_in[8];
    const float* fc_w   = (const float*)d_in[9];
    const float* fc_b   = (const float*)d_in[10];

    bigru_fused_kernel<<<dim3(Bb), dim3(64), 0, stream>>>(
        x, w_ih_f, w_hh_f, b_ih_f, b_hh_f,
        w_ih_b, w_hh_b, b_ih_b, b_hh_b, fc_w, fc_b,
        (float*)d_out);
}